// Round 19
// baseline (38.747 us; speedup 1.0000x reference)
//
#include <hip/hip_runtime.h>
#include <hip/hip_bf16.h>
#include <math.h>

typedef __attribute__((ext_vector_type(4))) float f32x4;

#define N 8192
#define D 256
#define INV_T 10.0f
#define EPSN 1e-8f
// exp(10*a - 10) == exp2(14.42695*a - 14.42695); v_exp_f32 is base-2 native.
#define EXP2_SCALE 14.426950408889634f

__device__ __forceinline__ void async16(void* lds, const void* g) {
  __builtin_amdgcn_global_load_lds(
      (const __attribute__((address_space(1))) void*)g,
      (__attribute__((address_space(3))) void*)lds,
      16, 0, 0);
}

// Sum over each 16-lane group via DPP row_shr adds (VALU pipe, no DS traffic).
// Result valid in lane 15 of each group.
__device__ __forceinline__ float rowsum16(float v) {
  v += __uint_as_float(__builtin_amdgcn_update_dpp(
      0u, __float_as_uint(v), 0x118, 0xf, 0xf, true));  // row_shr:8
  v += __uint_as_float(__builtin_amdgcn_update_dpp(
      0u, __float_as_uint(v), 0x114, 0xf, 0xf, true));  // row_shr:4
  v += __uint_as_float(__builtin_amdgcn_update_dpp(
      0u, __float_as_uint(v), 0x112, 0xf, 0xf, true));  // row_shr:2
  v += __uint_as_float(__builtin_amdgcn_update_dpp(
      0u, __float_as_uint(v), 0x111, 0xf, 0xf, true));  // row_shr:1
  return v;
}

// One wave per row: fp32 norm, fp8-e4m3 normalized row. Also zeroes rowsum+out.
__global__ __launch_bounds__(256) void normalize_k(const float* __restrict__ feats,
                                                   unsigned char* __restrict__ fn,
                                                   float* __restrict__ rowsum,
                                                   float* __restrict__ out) {
  int row = blockIdx.x * 4 + (threadIdx.x >> 6);
  int lane = threadIdx.x & 63;
  if (threadIdx.x < 4) rowsum[blockIdx.x * 4 + threadIdx.x] = 0.0f;
  if (blockIdx.x == 0 && threadIdx.x == 0) out[0] = 0.0f;
  float4 v = ((const float4*)(feats + (size_t)row * D))[lane];
  float ss = v.x * v.x + v.y * v.y + v.z * v.z + v.w * v.w;
#pragma unroll
  for (int off = 32; off; off >>= 1) ss += __shfl_xor(ss, off, 64);
  float inv = 1.0f / fmaxf(sqrtf(ss), EPSN);
  int w = __builtin_amdgcn_cvt_pk_fp8_f32(v.x * inv, v.y * inv, 0, false);
  w = __builtin_amdgcn_cvt_pk_fp8_f32(v.z * inv, v.w * inv, w, true);
  ((int*)(fn + (size_t)row * D))[lane] = w;
}

// Fused symmetric GEMM (C = fn*fn^T/T, fp8) + exp(C-10) row/col sums + pos.
// PAIRED tiles: each block computes a 128x256 strip = two adjacent 128^2
// triangular tiles sharing one A panel. 8 waves (2x4), each owns a full
// 64x64 sub-output of ONE sub-tile. BK=64, 16x16x32 fp8 MFMA, chunk-swizzled
// LDS, DPP row-reduce.
// TRIPLE buffer: tiles 0,1,2 staged in prologue (counted vmcnt 6/6/3/0);
// only buf0 is restaged (tile 3) -> ONE mid-loop WAR drain+barrier.
// setprio REMOVED: T5 evidence (m190) shows setprio is null-to-negative on
// barrier-synced 2-phase GEMM (only pays on 8-phase role-split schedules).
// launch_bounds (512,4): VGPR cap 128 -- acc[4][4]=64 regs MUST NOT spill.
// R13/R14/R15 lesson: adding a fused reduction tail to this kernel flips
// regalloc into spilling acc (VGPR 60-64, 4x regression) regardless of
// occupancy hints -- keep the final reduction a SEPARATE kernel.
__global__ __launch_bounds__(512, 4) void gemm_lse(const unsigned char* __restrict__ fn,
                                                   float* __restrict__ rowsum,
                                                   float* __restrict__ pos) {
  __shared__ unsigned char As[3][8192];    // 128 rows x 64B per buffer
  __shared__ unsigned char Bs[3][16384];   // 256 rows x 64B per buffer
  __shared__ float lrow[128];
  __shared__ float lcol[256];              // [subtile*128 + col]
  int tid = threadIdx.x;
  int wave = tid >> 6, lane = tid & 63;
  int wm = wave >> 2, wn = wave & 3;
  int hi = lane >> 4, lo = lane & 15;

  // XCD-chunked order over 1056 = 8*132 blocks (bijective).
  int b = blockIdx.x;
  int t = (b & 7) * 132 + (b >> 3);
  // Pair-row mapping: rows h=0..31, each with 2*(32-h) blocks.
  int h = (int)((65.0f - sqrtf((float)(4225 - 4 * t))) * 0.5f);
  h = h < 0 ? 0 : (h > 31 ? 31 : h);
  while (t < h * (65 - h)) --h;
  while (t >= (h + 1) * (64 - h)) ++h;
  int r = t - h * (65 - h);
  int bm = 2 * h + (r & 1);   // A-panel (row) tile, 0..63
  int p = h + (r >> 1);       // B pair index: bn in {2p, 2p+1}

  const unsigned char* ga = fn + (size_t)(bm * 128) * D;
  const unsigned char* gb = fn + (size_t)(p * 256) * D;

  // Staging: chunk swizzle c' = c ^ ((r>>1)&3) within 4-chunk (64B) rows.
  int da = tid, ra = da >> 2, caa = ((da & 3) ^ ((ra >> 1) & 3)) * 16;
  int d0 = tid, r0 = d0 >> 2, c0 = ((d0 & 3) ^ ((r0 >> 1) & 3)) * 16;
  int d1 = tid + 512, r1 = d1 >> 2, c1 = ((d1 & 3) ^ ((r1 >> 1) & 3)) * 16;
  auto stage = [&](int buf, int kt) {
    async16(&As[buf][da * 16], ga + (size_t)ra * D + kt * 64 + caa);
    async16(&Bs[buf][d0 * 16], gb + (size_t)r0 * D + kt * 64 + c0);
    async16(&Bs[buf][d1 * 16], gb + (size_t)r1 * D + kt * 64 + c1);
  };

  // Fragment-read offsets: element (R,k): chunk k>>4 stored at ^((R>>1)&3).
  int offA[4][2], offB[4][2];
#pragma unroll
  for (int m = 0; m < 4; ++m) {
    int R = wm * 64 + m * 16 + lo;
#pragma unroll
    for (int ks = 0; ks < 2; ++ks)
      offA[m][ks] = R * 64 + ((((ks << 1) | (hi >> 1)) ^ ((R >> 1) & 3)) << 4) +
                    ((hi & 1) << 3);
  }
#pragma unroll
  for (int n = 0; n < 4; ++n) {
    int R = wn * 64 + n * 16 + lo;  // B row within 256-row pair panel
#pragma unroll
    for (int ks = 0; ks < 2; ++ks)
      offB[n][ks] = R * 64 + ((((ks << 1) | (hi >> 1)) ^ ((R >> 1) & 3)) << 4) +
                    ((hi & 1) << 3);
  }

  f32x4 acc[4][4];
#pragma unroll
  for (int m = 0; m < 4; ++m)
#pragma unroll
    for (int n = 0; n < 4; ++n) acc[m][n] = (f32x4){0.f, 0.f, 0.f, 0.f};

  auto compute = [&](int buf) {
#pragma unroll
    for (int ks = 0; ks < 2; ++ks) {
      long long a[4], bb[4];
#pragma unroll
      for (int m = 0; m < 4; ++m)
        a[m] = *(const long long*)&As[buf][offA[m][ks]];
#pragma unroll
      for (int n = 0; n < 4; ++n)
        bb[n] = *(const long long*)&Bs[buf][offB[n][ks]];
#pragma unroll
      for (int m = 0; m < 4; ++m)
#pragma unroll
        for (int n = 0; n < 4; ++n)
          acc[m][n] = __builtin_amdgcn_mfma_f32_16x16x32_fp8_fp8(
              a[m], bb[n], acc[m][n], 0, 0, 0);
    }
  };

  stage(0, 0);          // 3 loads/thread
  stage(1, 1);          // 6 outstanding
  stage(2, 2);          // 9 outstanding
  if (tid < 128) lrow[tid] = 0.0f;
  if (tid < 256) lcol[tid] = 0.0f;

#pragma unroll
  for (int kt = 0; kt < 4; ++kt) {
    // Counted waits: tile-kt's own 3 loads are the oldest outstanding group.
    if (kt <= 1)      asm volatile("s_waitcnt vmcnt(6)" ::: "memory");
    else if (kt == 2) asm volatile("s_waitcnt vmcnt(3)" ::: "memory");
    else              asm volatile("s_waitcnt vmcnt(0)" ::: "memory");
    __builtin_amdgcn_s_barrier();        // all waves' tile-kt loads landed
    __builtin_amdgcn_sched_barrier(0);
    compute(kt % 3);
    if (kt == 0) {
      // WAR guard: only buf0 is ever re-staged (tile 3).
      asm volatile("s_waitcnt lgkmcnt(0)" ::: "memory");
      __builtin_amdgcn_sched_barrier(0);
      __builtin_amdgcn_s_barrier();      // everyone done reading buf0
      stage(0, 3);
    }
  }

  // Epilogue: wave owns 64x64 of sub-tile bnW. C frag: col=lo, row=hi*4+j.
  int bnW = 2 * p + (wn >> 1);
  bool wvalid = (bnW >= bm);
  bool isdiag = (bnW == bm);
  int rbase = wm * 64;
  int clocal = (wn & 1) * 64;  // col base within the 128-col sub-tile
  if (wvalid) {
    float ca[4] = {0.f, 0.f, 0.f, 0.f};
#pragma unroll
    for (int m = 0; m < 4; ++m) {
#pragma unroll
      for (int j = 0; j < 4; ++j) {
        int rloc = rbase + m * 16 + hi * 4 + j;
        float v = 0.f;
#pragma unroll
        for (int n = 0; n < 4; ++n) {
          float e = exp2f(fmaf(acc[m][n][j], EXP2_SCALE, -EXP2_SCALE));
          if (isdiag && rloc == clocal + n * 16 + lo) e = 0.f;
          v += e;
          ca[n] += e;
        }
        v = rowsum16(v);
        if (lo == 15) atomicAdd(&lrow[rloc], v);
      }
    }
    if (!isdiag) {
#pragma unroll
      for (int n = 0; n < 4; ++n) {
        float c = ca[n];
        c += __shfl_xor(c, 16, 64);
        c += __shfl_xor(c, 32, 64);
        if (hi == 0) atomicAdd(&lcol[wn * 64 + n * 16 + lo], c);
      }
    }
    // pos harvest: sub-tile (bm, bm+32): local diagonal = sim[i, i+4096].
    if (bnW == bm + 32) {
#pragma unroll
      for (int m = 0; m < 4; ++m) {
#pragma unroll
        for (int n = 0; n < 4; ++n) {
          if (wm * 64 + m * 16 == clocal + n * 16 && (lo >> 2) == hi) {
            int j = lo & 3;
            f32x4 a = acc[m][n];
            float pv = (j == 0) ? a[0] : (j == 1) ? a[1] : (j == 2) ? a[2] : a[3];
            pv *= INV_T;
            int gr = bm * 128 + wm * 64 + m * 16 + lo;
            pos[gr] = pv;
            pos[gr + N / 2] = pv;
          }
        }
      }
    }
  }
  __syncthreads();
  if (tid < 128) atomicAdd(&rowsum[bm * 128 + tid], lrow[tid]);
  if (tid < 256) {
    int bnX = 2 * p + (tid >> 7);
    if (bnX > bm) atomicAdd(&rowsum[bnX * 128 + (tid & 127)], lcol[tid]);
  }
}

// 32 blocks x 256 threads: one row each, partial-reduce, atomic accumulate.
__global__ __launch_bounds__(256) void final_k(const float* __restrict__ rowsum,
                                               const float* __restrict__ pos,
                                               float* __restrict__ out) {
  int tid = threadIdx.x;
  int i = blockIdx.x * 256 + tid;
  float s = 10.0f + __logf(rowsum[i]) - pos[i];
#pragma unroll
  for (int off = 32; off; off >>= 1) s += __shfl_xor(s, off, 64);
  __shared__ float red[4];
  if ((tid & 63) == 0) red[tid >> 6] = s;
  __syncthreads();
  if (tid == 0)
    atomicAdd(out, (red[0] + red[1] + red[2] + red[3]) * (1.0f / N));
}

extern "C" void kernel_launch(void* const* d_in, const int* in_sizes, int n_in,
                              void* d_out, int out_size, void* d_ws, size_t ws_size,
                              hipStream_t stream) {
  const float* feats = (const float*)d_in[0];
  float* out = (float*)d_out;
  char* ws = (char*)d_ws;
  unsigned char* fn = (unsigned char*)ws;                      // 2 MB fp8 normalized feats
  float* pos = (float*)(ws + 2 * 1024 * 1024);                 // 32 KB
  float* rowsum = (float*)(ws + 2 * 1024 * 1024 + 32 * 1024);  // 32 KB

  normalize_k<<<N / 4, 256, 0, stream>>>(feats, fn, rowsum, out);
  gemm_lse<<<1056, 512, 0, stream>>>(fn, rowsum, pos);
  final_k<<<32, 256, 0, stream>>>(rowsum, pos, out);
}

// Round 20
// 36.344 us; speedup vs baseline: 1.0661x; 1.0661x over previous
//
#include <hip/hip_runtime.h>
#include <hip/hip_bf16.h>
#include <math.h>

typedef __attribute__((ext_vector_type(4))) float f32x4;

#define N 8192
#define D 256
#define INV_T 10.0f
#define EPSN 1e-8f

__device__ __forceinline__ void async16(void* lds, const void* g) {
  __builtin_amdgcn_global_load_lds(
      (const __attribute__((address_space(1))) void*)g,
      (__attribute__((address_space(3))) void*)lds,
      16, 0, 0);
}

// Sum over each 16-lane group via DPP row_shr adds (VALU pipe, no DS traffic).
// Result valid in lane 15 of each group.
__device__ __forceinline__ float rowsum16(float v) {
  v += __uint_as_float(__builtin_amdgcn_update_dpp(
      0u, __float_as_uint(v), 0x118, 0xf, 0xf, true));  // row_shr:8
  v += __uint_as_float(__builtin_amdgcn_update_dpp(
      0u, __float_as_uint(v), 0x114, 0xf, 0xf, true));  // row_shr:4
  v += __uint_as_float(__builtin_amdgcn_update_dpp(
      0u, __float_as_uint(v), 0x112, 0xf, 0xf, true));  // row_shr:2
  v += __uint_as_float(__builtin_amdgcn_update_dpp(
      0u, __float_as_uint(v), 0x111, 0xf, 0xf, true));  // row_shr:1
  return v;
}

// One wave per row: fp32 norm, fp8-e4m3 normalized row. Also zeroes rowsum+out.
__global__ __launch_bounds__(256) void normalize_k(const float* __restrict__ feats,
                                                   unsigned char* __restrict__ fn,
                                                   float* __restrict__ rowsum,
                                                   float* __restrict__ out) {
  int row = blockIdx.x * 4 + (threadIdx.x >> 6);
  int lane = threadIdx.x & 63;
  if (threadIdx.x < 4) rowsum[blockIdx.x * 4 + threadIdx.x] = 0.0f;
  if (blockIdx.x == 0 && threadIdx.x == 0) out[0] = 0.0f;
  float4 v = ((const float4*)(feats + (size_t)row * D))[lane];
  float ss = v.x * v.x + v.y * v.y + v.z * v.z + v.w * v.w;
#pragma unroll
  for (int off = 32; off; off >>= 1) ss += __shfl_xor(ss, off, 64);
  float inv = 1.0f / fmaxf(sqrtf(ss), EPSN);
  int w = __builtin_amdgcn_cvt_pk_fp8_f32(v.x * inv, v.y * inv, 0, false);
  w = __builtin_amdgcn_cvt_pk_fp8_f32(v.z * inv, v.w * inv, w, true);
  ((int*)(fn + (size_t)row * D))[lane] = w;
}

// Fused symmetric GEMM (C = fn*fn^T/T, fp8) + exp(C-10) row/col sums + pos.
// PAIRED tiles: each block computes a 128x256 strip = two adjacent 128^2
// triangular tiles sharing one A panel. 8 waves (2x4), each owns a full
// 64x64 sub-output of ONE sub-tile. BK=64, 16x16x32 fp8 MFMA, chunk-swizzled
// LDS, DPP row-reduce.
// TRIPLE buffer: tiles 0,1,2 staged in prologue (counted vmcnt 6/6/3/0);
// only buf0 is restaged (tile 3) -> ONE mid-loop WAR drain+barrier.
// setprio KEPT: R19 A/B showed removing it costs +2.2 us here -- with 2
// independent blocks/CU, same-SIMD waves from different blocks are in
// different phases (role diversity), which is T5's paying regime.
// launch_bounds (512,4): VGPR cap 128 -- acc[4][4]=64 regs MUST NOT spill.
// R13/R14/R15 lesson: adding a fused reduction tail to this kernel flips
// regalloc into spilling acc (VGPR 60-64, 4x regression) regardless of
// occupancy hints -- keep the final reduction a SEPARATE kernel.
__global__ __launch_bounds__(512, 4) void gemm_lse(const unsigned char* __restrict__ fn,
                                                   float* __restrict__ rowsum,
                                                   float* __restrict__ pos) {
  __shared__ unsigned char As[3][8192];    // 128 rows x 64B per buffer
  __shared__ unsigned char Bs[3][16384];   // 256 rows x 64B per buffer
  __shared__ float lrow[128];
  __shared__ float lcol[256];              // [subtile*128 + col]
  int tid = threadIdx.x;
  int wave = tid >> 6, lane = tid & 63;
  int wm = wave >> 2, wn = wave & 3;
  int hi = lane >> 4, lo = lane & 15;

  // XCD-chunked order over 1056 = 8*132 blocks (bijective).
  int b = blockIdx.x;
  int t = (b & 7) * 132 + (b >> 3);
  // Pair-row mapping: rows h=0..31, each with 2*(32-h) blocks.
  int h = (int)((65.0f - sqrtf((float)(4225 - 4 * t))) * 0.5f);
  h = h < 0 ? 0 : (h > 31 ? 31 : h);
  while (t < h * (65 - h)) --h;
  while (t >= (h + 1) * (64 - h)) ++h;
  int r = t - h * (65 - h);
  int bm = 2 * h + (r & 1);   // A-panel (row) tile, 0..63
  int p = h + (r >> 1);       // B pair index: bn in {2p, 2p+1}

  const unsigned char* ga = fn + (size_t)(bm * 128) * D;
  const unsigned char* gb = fn + (size_t)(p * 256) * D;

  // Staging: chunk swizzle c' = c ^ ((r>>1)&3) within 4-chunk (64B) rows.
  int da = tid, ra = da >> 2, caa = ((da & 3) ^ ((ra >> 1) & 3)) * 16;
  int d0 = tid, r0 = d0 >> 2, c0 = ((d0 & 3) ^ ((r0 >> 1) & 3)) * 16;
  int d1 = tid + 512, r1 = d1 >> 2, c1 = ((d1 & 3) ^ ((r1 >> 1) & 3)) * 16;
  auto stage = [&](int buf, int kt) {
    async16(&As[buf][da * 16], ga + (size_t)ra * D + kt * 64 + caa);
    async16(&Bs[buf][d0 * 16], gb + (size_t)r0 * D + kt * 64 + c0);
    async16(&Bs[buf][d1 * 16], gb + (size_t)r1 * D + kt * 64 + c1);
  };

  // Fragment-read offsets: element (R,k): chunk k>>4 stored at ^((R>>1)&3).
  int offA[4][2], offB[4][2];
#pragma unroll
  for (int m = 0; m < 4; ++m) {
    int R = wm * 64 + m * 16 + lo;
#pragma unroll
    for (int ks = 0; ks < 2; ++ks)
      offA[m][ks] = R * 64 + ((((ks << 1) | (hi >> 1)) ^ ((R >> 1) & 3)) << 4) +
                    ((hi & 1) << 3);
  }
#pragma unroll
  for (int n = 0; n < 4; ++n) {
    int R = wn * 64 + n * 16 + lo;  // B row within 256-row pair panel
#pragma unroll
    for (int ks = 0; ks < 2; ++ks)
      offB[n][ks] = R * 64 + ((((ks << 1) | (hi >> 1)) ^ ((R >> 1) & 3)) << 4) +
                    ((hi & 1) << 3);
  }

  f32x4 acc[4][4];
#pragma unroll
  for (int m = 0; m < 4; ++m)
#pragma unroll
    for (int n = 0; n < 4; ++n) acc[m][n] = (f32x4){0.f, 0.f, 0.f, 0.f};

  auto compute = [&](int buf) {
#pragma unroll
    for (int ks = 0; ks < 2; ++ks) {
      long long a[4], bb[4];
#pragma unroll
      for (int m = 0; m < 4; ++m)
        a[m] = *(const long long*)&As[buf][offA[m][ks]];
#pragma unroll
      for (int n = 0; n < 4; ++n)
        bb[n] = *(const long long*)&Bs[buf][offB[n][ks]];
      __builtin_amdgcn_s_setprio(1);
#pragma unroll
      for (int m = 0; m < 4; ++m)
#pragma unroll
        for (int n = 0; n < 4; ++n)
          acc[m][n] = __builtin_amdgcn_mfma_f32_16x16x32_fp8_fp8(
              a[m], bb[n], acc[m][n], 0, 0, 0);
      __builtin_amdgcn_s_setprio(0);
    }
  };

  stage(0, 0);          // 3 loads/thread
  stage(1, 1);          // 6 outstanding
  stage(2, 2);          // 9 outstanding
  if (tid < 128) lrow[tid] = 0.0f;
  if (tid < 256) lcol[tid] = 0.0f;

#pragma unroll
  for (int kt = 0; kt < 4; ++kt) {
    // Counted waits: tile-kt's own 3 loads are the oldest outstanding group.
    if (kt <= 1)      asm volatile("s_waitcnt vmcnt(6)" ::: "memory");
    else if (kt == 2) asm volatile("s_waitcnt vmcnt(3)" ::: "memory");
    else              asm volatile("s_waitcnt vmcnt(0)" ::: "memory");
    __builtin_amdgcn_s_barrier();        // all waves' tile-kt loads landed
    __builtin_amdgcn_sched_barrier(0);
    compute(kt % 3);
    if (kt == 0) {
      // WAR guard: only buf0 is ever re-staged (tile 3).
      asm volatile("s_waitcnt lgkmcnt(0)" ::: "memory");
      __builtin_amdgcn_sched_barrier(0);
      __builtin_amdgcn_s_barrier();      // everyone done reading buf0
      stage(0, 3);
    }
  }

  // Epilogue: wave owns 64x64 of sub-tile bnW. C frag: col=lo, row=hi*4+j.
  int bnW = 2 * p + (wn >> 1);
  bool wvalid = (bnW >= bm);
  bool isdiag = (bnW == bm);
  int rbase = wm * 64;
  int clocal = (wn & 1) * 64;  // col base within the 128-col sub-tile
  if (wvalid) {
    float ca[4] = {0.f, 0.f, 0.f, 0.f};
#pragma unroll
    for (int m = 0; m < 4; ++m) {
#pragma unroll
      for (int j = 0; j < 4; ++j) {
        int rloc = rbase + m * 16 + hi * 4 + j;
        float v = 0.f;
#pragma unroll
        for (int n = 0; n < 4; ++n) {
          float e = __expf(fmaf(acc[m][n][j], 10.0f, -10.0f));
          if (isdiag && rloc == clocal + n * 16 + lo) e = 0.f;
          v += e;
          ca[n] += e;
        }
        v = rowsum16(v);
        if (lo == 15) atomicAdd(&lrow[rloc], v);
      }
    }
    if (!isdiag) {
#pragma unroll
      for (int n = 0; n < 4; ++n) {
        float c = ca[n];
        c += __shfl_xor(c, 16, 64);
        c += __shfl_xor(c, 32, 64);
        if (hi == 0) atomicAdd(&lcol[wn * 64 + n * 16 + lo], c);
      }
    }
    // pos harvest: sub-tile (bm, bm+32): local diagonal = sim[i, i+4096].
    if (bnW == bm + 32) {
#pragma unroll
      for (int m = 0; m < 4; ++m) {
#pragma unroll
        for (int n = 0; n < 4; ++n) {
          if (wm * 64 + m * 16 == clocal + n * 16 && (lo >> 2) == hi) {
            int j = lo & 3;
            f32x4 a = acc[m][n];
            float pv = (j == 0) ? a[0] : (j == 1) ? a[1] : (j == 2) ? a[2] : a[3];
            pv *= INV_T;
            int gr = bm * 128 + wm * 64 + m * 16 + lo;
            pos[gr] = pv;
            pos[gr + N / 2] = pv;
          }
        }
      }
    }
  }
  __syncthreads();
  if (tid < 128) atomicAdd(&rowsum[bm * 128 + tid], lrow[tid]);
  if (tid < 256) {
    int bnX = 2 * p + (tid >> 7);
    if (bnX > bm) atomicAdd(&rowsum[bnX * 128 + (tid & 127)], lcol[tid]);
  }
}

// 32 blocks x 256 threads: one row each, partial-reduce, atomic accumulate.
__global__ __launch_bounds__(256) void final_k(const float* __restrict__ rowsum,
                                               const float* __restrict__ pos,
                                               float* __restrict__ out) {
  int tid = threadIdx.x;
  int i = blockIdx.x * 256 + tid;
  float s = 10.0f + __logf(rowsum[i]) - pos[i];
#pragma unroll
  for (int off = 32; off; off >>= 1) s += __shfl_xor(s, off, 64);
  __shared__ float red[4];
  if ((tid & 63) == 0) red[tid >> 6] = s;
  __syncthreads();
  if (tid == 0)
    atomicAdd(out, (red[0] + red[1] + red[2] + red[3]) * (1.0f / N));
}

extern "C" void kernel_launch(void* const* d_in, const int* in_sizes, int n_in,
                              void* d_out, int out_size, void* d_ws, size_t ws_size,
                              hipStream_t stream) {
  const float* feats = (const float*)d_in[0];
  float* out = (float*)d_out;
  char* ws = (char*)d_ws;
  unsigned char* fn = (unsigned char*)ws;                      // 2 MB fp8 normalized feats
  float* pos = (float*)(ws + 2 * 1024 * 1024);                 // 32 KB
  float* rowsum = (float*)(ws + 2 * 1024 * 1024 + 32 * 1024);  // 32 KB

  normalize_k<<<N / 4, 256, 0, stream>>>(feats, fn, rowsum, out);
  gemm_lse<<<1056, 512, 0, stream>>>(fn, rowsum, pos);
  final_k<<<32, 256, 0, stream>>>(rowsum, pos, out);
}